// Round 9
// baseline (103.672 us; speedup 1.0000x reference)
//
#include <hip/hip_runtime.h>

#define BATCH 64
#define TLEN  2048
#define DDIM  256
#define ADIM  128
#define TM    64          // t-rows per tile
#define TILES 4           // tiles per block
#define EPSC  1e-7f

typedef __bf16 bf16x8 __attribute__((ext_vector_type(8)));
typedef float  f32x4  __attribute__((ext_vector_type(4)));

// DPP-based add of a lane-permuted copy (VALU pipe, not LDS)
template <int CTRL>
__device__ __forceinline__ float dpp_add(float v) {
    int vi = __builtin_bit_cast(int, v);
    int sw = __builtin_amdgcn_update_dpp(vi, vi, CTRL, 0xF, 0xF, false);
    return v + __builtin_bit_cast(float, sw);
}

// raw workgroup barrier: orders LDS only, leaves global loads (vmcnt) in flight
__device__ __forceinline__ void bar_lds() {
    asm volatile("s_waitcnt lgkmcnt(0)" ::: "memory");
    __builtin_amdgcn_s_barrier();
}

// ws layout:
//   [0,      65536)  : Wf  bf16[32768]  (B-fragment-ordered W)
//   [65536, 131072)  : N   f32[16384]   (unnormalized numerator, per b,d)
//   [131072,131328)  : s   f32[64]      (unnormalized denominator, per b)

__global__ __launch_bounds__(256) void prep_kernel(const float* __restrict__ W,
                                                   __bf16* __restrict__ Wf,
                                                   float* __restrict__ N,
                                                   float* __restrict__ s) {
    int idx = blockIdx.x * 256 + threadIdx.x;   // [0, 32768)
    int j  = idx & 7;
    int l  = (idx >> 3) & 63;
    int nt = (idx >> 9) & 7;
    int kt = idx >> 12;
    int k = kt * 32 + (l >> 4) * 8 + j;         // K index into D
    int n = nt * 16 + (l & 15);                 // N index into A
    Wf[idx] = (__bf16)W[k * ADIM + n];
    if (idx < BATCH * DDIM) N[idx] = 0.0f;
    if (idx >= BATCH * DDIM && idx < BATCH * DDIM + BATCH) s[idx - BATCH * DDIM] = 0.0f;
}

__global__ __launch_bounds__(256, 3) void attn_main(const float* __restrict__ x,
                                                    const float* __restrict__ bias,
                                                    const float* __restrict__ u,
                                                    const __bf16* __restrict__ Wf,
                                                    float* __restrict__ N,
                                                    float* __restrict__ s) {
    __shared__ char  xs[TM * DDIM * 2];      // 32 KB single buffer, XOR-swizzled
    __shared__ float wpart[4][TM];           // per-wave 32-col row partials (1 KB)
    __shared__ float fpart[4][32][8];        // pooling partials (4 KB)
    __shared__ float ssum_lds[4];

    const int b    = blockIdx.x >> 3;            // 8 blocks per batch
    const int t00  = (blockIdx.x & 7) * (TILES * TM);
    const int tid  = threadIdx.x;
    const int wave = tid >> 6;
    const int lane = tid & 63;
    const int lm   = lane & 15;                  // col index within 16x16 C tile
    const int lk   = lane >> 4;                  // k-block / row-quad index
    const int row  = wave * 16 + lm;             // local row this thread stages

    // wave w owns A-columns [w*32, w*32+32)
    float bias_r[2], u_r[2];
#pragma unroll
    for (int ntl = 0; ntl < 2; ++ntl) {
        bias_r[ntl] = bias[wave * 32 + ntl * 16 + lm];
        u_r[ntl]    = u[wave * 32 + ntl * 16 + lm];
    }

    // hoist Wf fragments for this wave's 2 n-tiles across all kt (64 VGPRs)
    bf16x8 wfreg[8][2];
#pragma unroll
    for (int kt = 0; kt < 8; ++kt)
#pragma unroll
        for (int ntl = 0; ntl < 2; ++ntl)
            wfreg[kt][ntl] = *(const bf16x8*)(Wf + ((size_t)((kt * 8 + wave * 2 + ntl) * 64 + lane)) * 8);

    float vacc[8] = {0.f, 0.f, 0.f, 0.f, 0.f, 0.f, 0.f, 0.f};
    float sreg = 0.f;                   // per-thread denominator partial (x32 overcount)
    const int dgrp = tid & 31;          // pooling: d = dgrp*8 + j
    const int tgrp = tid >> 5;          // pooling: t = tgrp*8 + i

    const float* xbase = x + ((size_t)(b * TLEN + t00 + row)) * DDIM;

    // ---- prologue: load tile 0 into registers ----
    f32x4 fa[8], fb[8];
#pragma unroll
    for (int kt = 0; kt < 8; ++kt) {
        fa[kt] = *(const f32x4*)(xbase + kt * 32 + lk * 8);
        fb[kt] = *(const f32x4*)(xbase + kt * 32 + lk * 8 + 4);
    }

    for (int it = 0; it < TILES; ++it) {
        // ---- phase 1: cvt + stash current tile; then issue next tile's loads ----
#pragma unroll
        for (int kt = 0; kt < 8; ++kt) {
            bf16x8 a;
#pragma unroll
            for (int i = 0; i < 4; ++i) { a[i] = (__bf16)fa[kt][i]; a[4 + i] = (__bf16)fb[kt][i]; }
            *(bf16x8*)(xs + ((row * 512 + (kt * 32 + lk * 8) * 2) ^ ((row & 7) << 4))) = a;
        }
        if (it + 1 < TILES) {
            const float* xn = xbase + (size_t)(it + 1) * TM * DDIM;
#pragma unroll
            for (int kt = 0; kt < 8; ++kt) {
                fa[kt] = *(const f32x4*)(xn + kt * 32 + lk * 8);
                fb[kt] = *(const f32x4*)(xn + kt * 32 + lk * 8 + 4);
            }
        }
        bar_lds();   // stash visible; prefetch stays in flight (no vmcnt drain)

        // ---- phase 2: GEMM (A from LDS, W from regs) + logits -> wpart ----
        f32x4 acc[4][2];
#pragma unroll
        for (int m = 0; m < 4; ++m)
#pragma unroll
            for (int ntl = 0; ntl < 2; ++ntl) acc[m][ntl] = (f32x4){0.f, 0.f, 0.f, 0.f};

#pragma unroll
        for (int kt = 0; kt < 8; ++kt) {
#pragma unroll
            for (int m = 0; m < 4; ++m) {
                const int r = m * 16 + lm;
                bf16x8 afrag = *(const bf16x8*)(xs + ((r * 512 + (kt * 32 + lk * 8) * 2) ^ ((r & 7) << 4)));
                acc[m][0] = __builtin_amdgcn_mfma_f32_16x16x32_bf16(afrag, wfreg[kt][0], acc[m][0], 0, 0, 0);
                acc[m][1] = __builtin_amdgcn_mfma_f32_16x16x32_bf16(afrag, wfreg[kt][1], acc[m][1], 0, 0, 0);
            }
        }

#pragma unroll
        for (int m = 0; m < 4; ++m) {
#pragma unroll
            for (int reg = 0; reg < 4; ++reg) {
                float p = 0.f;
#pragma unroll
                for (int ntl = 0; ntl < 2; ++ntl) {
                    float lg = acc[m][ntl][reg] + bias_r[ntl];
                    float e  = __expf(2.0f * lg);
                    float th = 1.0f - 2.0f * __builtin_amdgcn_rcpf(e + 1.0f);  // tanh, inf-safe
                    p += th * u_r[ntl];
                }
                p = dpp_add<0xB1>(p);   // xor 1
                p = dpp_add<0x4E>(p);   // xor 2
                p = dpp_add<0x141>(p);  // row_half_mirror
                p = dpp_add<0x140>(p);  // row_mirror -> full 16-lane sum
                if (lm == 0) wpart[wave][m * 16 + lk * 4 + reg] = p;
            }
        }
        bar_lds();

        // ---- phase 3: every thread computes z/exp for its 8 rows, then pools ----
        f32x4 zlo = (f32x4){0.f, 0.f, 0.f, 0.f}, zhi = (f32x4){0.f, 0.f, 0.f, 0.f};
#pragma unroll
        for (int w = 0; w < 4; ++w) {
            zlo += *(const f32x4*)&wpart[w][tgrp * 8];
            zhi += *(const f32x4*)&wpart[w][tgrp * 8 + 4];
        }
        float wv[8];
#pragma unroll
        for (int i = 0; i < 4; ++i) { wv[i] = __expf(zlo[i]); wv[4 + i] = __expf(zhi[i]); }
#pragma unroll
        for (int i = 0; i < 8; ++i) sreg += wv[i];

#pragma unroll
        for (int i = 0; i < 8; ++i) {
            const int t = tgrp * 8 + i;
            bf16x8 xv = *(const bf16x8*)(xs + ((t * 512 + dgrp * 16) ^ ((t & 7) << 4)));
#pragma unroll
            for (int j = 0; j < 8; ++j) vacc[j] += (float)xv[j] * wv[i];
        }
        bar_lds();   // xs / wpart free for next tile
    }

    // ---- epilogue: denominator (each row counted 32x across dgrp) ----
    float ss = sreg;
#pragma unroll
    for (int off = 1; off < 64; off <<= 1) ss += __shfl_xor(ss, off);
    if (lane == 0) ssum_lds[wave] = ss;

    // ---- epilogue: numerator ----
#pragma unroll
    for (int j = 0; j < 8; ++j) vacc[j] += __shfl_xor(vacc[j], 32);
    if (lane < 32) {
        *(f32x4*)&fpart[wave][dgrp][0] = (f32x4){vacc[0], vacc[1], vacc[2], vacc[3]};
        *(f32x4*)&fpart[wave][dgrp][4] = (f32x4){vacc[4], vacc[5], vacc[6], vacc[7]};
    }
    __syncthreads();
    if (tid == 0) {
        float st = (ssum_lds[0] + ssum_lds[1] + ssum_lds[2] + ssum_lds[3]) * (1.0f / 32.0f);
        atomicAdd(&s[b], st);
    }
    float r = fpart[0][tid >> 3][tid & 7] + fpart[1][tid >> 3][tid & 7]
            + fpart[2][tid >> 3][tid & 7] + fpart[3][tid >> 3][tid & 7];
    atomicAdd(&N[b * DDIM + tid], r);
}

__global__ __launch_bounds__(256) void finalize_kernel(const float* __restrict__ N,
                                                       const float* __restrict__ s,
                                                       float* __restrict__ out) {
    int idx = blockIdx.x * 256 + threadIdx.x;   // [0, 16384)
    out[idx] = N[idx] / (s[idx >> 8] + EPSC);
}

extern "C" void kernel_launch(void* const* d_in, const int* in_sizes, int n_in,
                              void* d_out, int out_size, void* d_ws, size_t ws_size,
                              hipStream_t stream) {
    const float* x    = (const float*)d_in[0];
    const float* W    = (const float*)d_in[1];
    const float* bias = (const float*)d_in[2];
    const float* u    = (const float*)d_in[3];
    float* out = (float*)d_out;

    char* ws = (char*)d_ws;
    __bf16* Wf = (__bf16*)ws;
    float*  N  = (float*)(ws + 65536);
    float*  s  = (float*)(ws + 131072);

    prep_kernel<<<128, 256, 0, stream>>>(W, Wf, N, s);
    attn_main<<<BATCH * TLEN / (TILES * TM), 256, 0, stream>>>(x, bias, u, Wf, N, s);
    finalize_kernel<<<(BATCH * DDIM) / 256, 256, 0, stream>>>(N, s, out);
}

// Round 10
// 41.111 us; speedup vs baseline: 2.5218x; 2.5218x over previous
//
#include <hip/hip_runtime.h>

#define BATCH 64
#define TLEN  2048
#define DDIM  256
#define ADIM  128
#define TM    64          // t-rows per tile
#define TILES 4           // tiles per block
#define EPSC  1e-7f

typedef __bf16 bf16x8 __attribute__((ext_vector_type(8)));
typedef float  f32x4  __attribute__((ext_vector_type(4)));

// DPP-based add of a lane-permuted copy (VALU pipe, not LDS)
template <int CTRL>
__device__ __forceinline__ float dpp_add(float v) {
    int vi = __builtin_bit_cast(int, v);
    int sw = __builtin_amdgcn_update_dpp(vi, vi, CTRL, 0xF, 0xF, false);
    return v + __builtin_bit_cast(float, sw);
}

// raw workgroup barrier: orders LDS only, leaves global loads (vmcnt) in flight
__device__ __forceinline__ void bar_lds() {
    asm volatile("s_waitcnt lgkmcnt(0)" ::: "memory");
    __builtin_amdgcn_s_barrier();
}

// ws layout:
//   [0,      65536)  : Wf  bf16[32768]  (B-fragment-ordered W)
//   [65536, 131072)  : N   f32[16384]   (unnormalized numerator, per b,d)
//   [131072,131328)  : s   f32[64]      (unnormalized denominator, per b)

__global__ __launch_bounds__(256) void prep_kernel(const float* __restrict__ W,
                                                   __bf16* __restrict__ Wf,
                                                   float* __restrict__ N,
                                                   float* __restrict__ s) {
    int idx = blockIdx.x * 256 + threadIdx.x;   // [0, 32768)
    int j  = idx & 7;
    int l  = (idx >> 3) & 63;
    int nt = (idx >> 9) & 7;
    int kt = idx >> 12;
    int k = kt * 32 + (l >> 4) * 8 + j;         // K index into D
    int n = nt * 16 + (l & 15);                 // N index into A
    Wf[idx] = (__bf16)W[k * ADIM + n];
    if (idx < BATCH * DDIM) N[idx] = 0.0f;
    if (idx >= BATCH * DDIM && idx < BATCH * DDIM + BATCH) s[idx - BATCH * DDIM] = 0.0f;
}

__global__ __launch_bounds__(256, 2) void attn_main(const float* __restrict__ x,
                                                    const float* __restrict__ bias,
                                                    const float* __restrict__ u,
                                                    const __bf16* __restrict__ Wf,
                                                    float* __restrict__ N,
                                                    float* __restrict__ s) {
    __shared__ char  xs[TM * DDIM * 2];      // 32 KB single buffer, XOR-swizzled
    __shared__ float wpart[4][TM];           // per-wave 32-col row partials (1 KB)
    __shared__ float fpart[4][32][8];        // pooling partials (4 KB)
    __shared__ float ssum_lds[4];

    const int b    = blockIdx.x >> 3;            // 8 blocks per batch
    const int t00  = (blockIdx.x & 7) * (TILES * TM);
    const int tid  = threadIdx.x;
    const int wave = tid >> 6;
    const int lane = tid & 63;
    const int lm   = lane & 15;                  // col index within 16x16 C tile
    const int lk   = lane >> 4;                  // k-block / row-quad index
    const int row  = wave * 16 + lm;             // local row this thread stages

    // wave w owns A-columns [w*32, w*32+32)
    float bias_r[2], u_r[2];
#pragma unroll
    for (int ntl = 0; ntl < 2; ++ntl) {
        bias_r[ntl] = bias[wave * 32 + ntl * 16 + lm];
        u_r[ntl]    = u[wave * 32 + ntl * 16 + lm];
    }

    // hoist Wf fragments for this wave's 2 n-tiles across all kt (64 VGPRs)
    bf16x8 wfreg[8][2];
#pragma unroll
    for (int kt = 0; kt < 8; ++kt)
#pragma unroll
        for (int ntl = 0; ntl < 2; ++ntl)
            wfreg[kt][ntl] = *(const bf16x8*)(Wf + ((size_t)((kt * 8 + wave * 2 + ntl) * 64 + lane)) * 8);

    float vacc[8] = {0.f, 0.f, 0.f, 0.f, 0.f, 0.f, 0.f, 0.f};
    float sreg = 0.f;                   // per-thread denominator partial (x32 overcount)
    const int dgrp = tid & 31;          // pooling: d = dgrp*8 + j
    const int tgrp = tid >> 5;          // pooling: t = tgrp*8 + i

    const float* xbase = x + ((size_t)(b * TLEN + t00 + row)) * DDIM;

    // ---- prologue: load tile 0 into registers ----
    f32x4 fa[8], fb[8];
#pragma unroll
    for (int kt = 0; kt < 8; ++kt) {
        fa[kt] = *(const f32x4*)(xbase + kt * 32 + lk * 8);
        fb[kt] = *(const f32x4*)(xbase + kt * 32 + lk * 8 + 4);
    }

    for (int it = 0; it < TILES; ++it) {
        // ---- phase 1: cvt + stash current tile; then issue next tile's loads ----
#pragma unroll
        for (int kt = 0; kt < 8; ++kt) {
            bf16x8 a;
#pragma unroll
            for (int i = 0; i < 4; ++i) { a[i] = (__bf16)fa[kt][i]; a[4 + i] = (__bf16)fb[kt][i]; }
            *(bf16x8*)(xs + ((row * 512 + (kt * 32 + lk * 8) * 2) ^ ((row & 7) << 4))) = a;
        }
        if (it + 1 < TILES) {
            const float* xn = xbase + (size_t)(it + 1) * TM * DDIM;
#pragma unroll
            for (int kt = 0; kt < 8; ++kt) {
                fa[kt] = *(const f32x4*)(xn + kt * 32 + lk * 8);
                fb[kt] = *(const f32x4*)(xn + kt * 32 + lk * 8 + 4);
            }
        }
        bar_lds();   // stash visible; prefetch stays in flight (no vmcnt drain)

        // ---- phase 2: GEMM (A from LDS, W from regs) + logits -> wpart ----
        f32x4 acc[4][2];
#pragma unroll
        for (int m = 0; m < 4; ++m)
#pragma unroll
            for (int ntl = 0; ntl < 2; ++ntl) acc[m][ntl] = (f32x4){0.f, 0.f, 0.f, 0.f};

#pragma unroll
        for (int kt = 0; kt < 8; ++kt) {
#pragma unroll
            for (int m = 0; m < 4; ++m) {
                const int r = m * 16 + lm;
                bf16x8 afrag = *(const bf16x8*)(xs + ((r * 512 + (kt * 32 + lk * 8) * 2) ^ ((r & 7) << 4)));
                acc[m][0] = __builtin_amdgcn_mfma_f32_16x16x32_bf16(afrag, wfreg[kt][0], acc[m][0], 0, 0, 0);
                acc[m][1] = __builtin_amdgcn_mfma_f32_16x16x32_bf16(afrag, wfreg[kt][1], acc[m][1], 0, 0, 0);
            }
        }

#pragma unroll
        for (int m = 0; m < 4; ++m) {
#pragma unroll
            for (int reg = 0; reg < 4; ++reg) {
                float p = 0.f;
#pragma unroll
                for (int ntl = 0; ntl < 2; ++ntl) {
                    float lg = acc[m][ntl][reg] + bias_r[ntl];
                    float e  = __expf(2.0f * lg);
                    float th = 1.0f - 2.0f * __builtin_amdgcn_rcpf(e + 1.0f);  // tanh, inf-safe
                    p += th * u_r[ntl];
                }
                p = dpp_add<0xB1>(p);   // xor 1
                p = dpp_add<0x4E>(p);   // xor 2
                p = dpp_add<0x141>(p);  // row_half_mirror
                p = dpp_add<0x140>(p);  // row_mirror -> full 16-lane sum
                if (lm == 0) wpart[wave][m * 16 + lk * 4 + reg] = p;
            }
        }
        bar_lds();

        // ---- phase 3: every thread computes z/exp for its 8 rows, then pools ----
        f32x4 zlo = (f32x4){0.f, 0.f, 0.f, 0.f}, zhi = (f32x4){0.f, 0.f, 0.f, 0.f};
#pragma unroll
        for (int w = 0; w < 4; ++w) {
            zlo += *(const f32x4*)&wpart[w][tgrp * 8];
            zhi += *(const f32x4*)&wpart[w][tgrp * 8 + 4];
        }
        float wv[8];
#pragma unroll
        for (int i = 0; i < 4; ++i) { wv[i] = __expf(zlo[i]); wv[4 + i] = __expf(zhi[i]); }
#pragma unroll
        for (int i = 0; i < 8; ++i) sreg += wv[i];

#pragma unroll
        for (int i = 0; i < 8; ++i) {
            const int t = tgrp * 8 + i;
            bf16x8 xv = *(const bf16x8*)(xs + ((t * 512 + dgrp * 16) ^ ((t & 7) << 4)));
#pragma unroll
            for (int j = 0; j < 8; ++j) vacc[j] += (float)xv[j] * wv[i];
        }
        bar_lds();   // xs / wpart free for next tile
    }

    // ---- epilogue: denominator (each row counted 32x across dgrp) ----
    float ss = sreg;
#pragma unroll
    for (int off = 1; off < 64; off <<= 1) ss += __shfl_xor(ss, off);
    if (lane == 0) ssum_lds[wave] = ss;

    // ---- epilogue: numerator ----
#pragma unroll
    for (int j = 0; j < 8; ++j) vacc[j] += __shfl_xor(vacc[j], 32);
    if (lane < 32) {
        *(f32x4*)&fpart[wave][dgrp][0] = (f32x4){vacc[0], vacc[1], vacc[2], vacc[3]};
        *(f32x4*)&fpart[wave][dgrp][4] = (f32x4){vacc[4], vacc[5], vacc[6], vacc[7]};
    }
    __syncthreads();
    if (tid == 0) {
        float st = (ssum_lds[0] + ssum_lds[1] + ssum_lds[2] + ssum_lds[3]) * (1.0f / 32.0f);
        atomicAdd(&s[b], st);
    }
    float r = fpart[0][tid >> 3][tid & 7] + fpart[1][tid >> 3][tid & 7]
            + fpart[2][tid >> 3][tid & 7] + fpart[3][tid >> 3][tid & 7];
    atomicAdd(&N[b * DDIM + tid], r);
}

__global__ __launch_bounds__(256) void finalize_kernel(const float* __restrict__ N,
                                                       const float* __restrict__ s,
                                                       float* __restrict__ out) {
    int idx = blockIdx.x * 256 + threadIdx.x;   // [0, 16384)
    out[idx] = N[idx] / (s[idx >> 8] + EPSC);
}

extern "C" void kernel_launch(void* const* d_in, const int* in_sizes, int n_in,
                              void* d_out, int out_size, void* d_ws, size_t ws_size,
                              hipStream_t stream) {
    const float* x    = (const float*)d_in[0];
    const float* W    = (const float*)d_in[1];
    const float* bias = (const float*)d_in[2];
    const float* u    = (const float*)d_in[3];
    float* out = (float*)d_out;

    char* ws = (char*)d_ws;
    __bf16* Wf = (__bf16*)ws;
    float*  N  = (float*)(ws + 65536);
    float*  s  = (float*)(ws + 131072);

    prep_kernel<<<128, 256, 0, stream>>>(W, Wf, N, s);
    attn_main<<<BATCH * TLEN / (TILES * TM), 256, 0, stream>>>(x, bias, u, Wf, N, s);
    finalize_kernel<<<(BATCH * DDIM) / 256, 256, 0, stream>>>(N, s, out);
}